// Round 6
// baseline (4546.007 us; speedup 1.0000x reference)
//
#include <hip/hip_runtime.h>
#include <hip/hip_bf16.h>
#include <math.h>

#define B    64
#define T    256
#define H    1024
#define G4   4096
#define TC   64           // timesteps per x_proj chunk
#define NCH  (T / TC)
#define NBLK 64           // persistent blocks (16 h-cols each)
#define FSTR 16           // flag stride in ints (64B apart)

typedef __attribute__((ext_vector_type(8))) short bf16x8;
typedef __attribute__((ext_vector_type(4))) float f32x4;

__device__ __forceinline__ unsigned short f2bf(float x) {
    union { float f; unsigned u; } v; v.f = x;
    unsigned r = v.u + 0x7fffu + ((v.u >> 16) & 1u);   // RNE
    return (unsigned short)(r >> 16);
}
__device__ __forceinline__ float bf2f(unsigned short s) {
    union { unsigned u; float f; } v; v.u = ((unsigned)s) << 16;
    return v.f;
}
__device__ __forceinline__ float sigm_f(float x) {
    return 1.f / (1.f + __expf(-x));
}
__device__ __forceinline__ float tanh_f(float x) {
    float e = __expf(2.f * x);
    return (e - 1.f) / (e + 1.f);
}

// ---------------------------------------------------------------------------
__global__ __launch_bounds__(256) void cast_f32_bf16(
    const float* __restrict__ src, unsigned short* __restrict__ dst, int n8)
{
    int i = blockIdx.x * 256 + threadIdx.x;
    if (i >= n8) return;
    const float4* s = (const float4*)(src + (size_t)i * 8);
    float4 a = s[0], b = s[1];
    bf16x8 o;
    o[0] = f2bf(a.x); o[1] = f2bf(a.y); o[2] = f2bf(a.z); o[3] = f2bf(a.w);
    o[4] = f2bf(b.x); o[5] = f2bf(b.y); o[6] = f2bf(b.z); o[7] = f2bf(b.w);
    *(bf16x8*)(dst + (size_t)i * 8) = o;
}

// ---------------------------------------------------------------------------
__global__ __launch_bounds__(256) void gather_x(
    const int* __restrict__ tgt, const float* __restrict__ emb,
    unsigned short* __restrict__ xch, int t0)
{
    int tid = threadIdx.x;
    int r   = blockIdx.x * 2 + (tid >> 7);     // 0..4095
    int c   = (tid & 127) * 8;
    int b   = r & 63, tcc = r >> 6;
    int token = tgt[b * T + t0 + tcc];
    const float4* s = (const float4*)(emb + (size_t)token * H + c);
    float4 x0 = s[0], x1 = s[1];
    bf16x8 o;
    o[0] = f2bf(x0.x); o[1] = f2bf(x0.y); o[2] = f2bf(x0.z); o[3] = f2bf(x0.w);
    o[4] = f2bf(x1.x); o[5] = f2bf(x1.y); o[6] = f2bf(x1.z); o[7] = f2bf(x1.w);
    *(bf16x8*)(xch + (size_t)r * H + c) = o;
}

// ---------------------------------------------------------------------------
// x_proj chunk GEMM (unchanged — proven since round 2)
// ---------------------------------------------------------------------------
__global__ __launch_bounds__(256) void gemm_xproj(
    const unsigned short* __restrict__ A,   // x chunk bf16 [4096][1024]
    const unsigned short* __restrict__ Bt,  // W_ih bf16 [4096][1024]
    unsigned short* __restrict__ C)         // [4096][4096]
{
    __shared__ unsigned short As[128 * 64], Bs[128 * 64];
    const int tid  = threadIdx.x;
    const int brow = (blockIdx.x >> 5) * 128;
    const int bcol = (blockIdx.x & 31) * 128;
    const int w = tid >> 6, lane = tid & 63;
    const int wr = w >> 1, wc = w & 1;
    const int lr = lane & 15, lg = lane >> 4;

    f32x4 acc[4][4] = {};

    for (int kc = 0; kc < H; kc += 64) {
        if (kc) __syncthreads();
        #pragma unroll
        for (int i = 0; i < 4; ++i) {
            int sf  = i * 256 + tid;
            int row = sf >> 3, s = sf & 7;
            int col = kc + s * 8;
            *(bf16x8*)(As + row * 64 + ((s ^ (row & 7)) * 8)) =
                *(const bf16x8*)(A + (size_t)(brow + row) * H + col);
            *(bf16x8*)(Bs + row * 64 + ((s ^ (row & 7)) * 8)) =
                *(const bf16x8*)(Bt + (size_t)(bcol + row) * H + col);
        }
        __syncthreads();
        #pragma unroll
        for (int kk = 0; kk < 2; ++kk) {
            bf16x8 af[4], bv[4];
            #pragma unroll
            for (int m = 0; m < 4; ++m) {
                int row = wr * 64 + m * 16 + lr;
                int s   = kk * 4 + lg;
                af[m] = *(const bf16x8*)(As + row * 64 + ((s ^ (row & 7)) * 8));
            }
            #pragma unroll
            for (int n = 0; n < 4; ++n) {
                int row = wc * 64 + n * 16 + lr;
                int s   = kk * 4 + lg;
                bv[n] = *(const bf16x8*)(Bs + row * 64 + ((s ^ (row & 7)) * 8));
            }
            #pragma unroll
            for (int m = 0; m < 4; ++m)
                #pragma unroll
                for (int n = 0; n < 4; ++n)
                    acc[m][n] = __builtin_amdgcn_mfma_f32_16x16x32_bf16(
                        af[m], bv[n], acc[m][n], 0, 0, 0);
        }
    }
    #pragma unroll
    for (int m = 0; m < 4; ++m)
        #pragma unroll
        for (int n = 0; n < 4; ++n)
            #pragma unroll
            for (int r = 0; r < 4; ++r) {
                int row = brow + wr * 64 + m * 16 + lg * 4 + r;
                int col = bcol + wc * 64 + n * 16 + lr;
                C[(size_t)row * G4 + col] = f2bf(acc[m][n][r]);
            }
}

// ---------------------------------------------------------------------------
// persistent chunk recurrence with TWO interleaved batch-chains.
// 64 blocks x 512 thr (cooperative launch for co-residency; no grid.sync).
// Block jb owns h-cols [16jb,16jb+16) x 4 gates = 64 W_hh rows in LDS (128KB,
// XOR-swizzled). Chains: batch rows [0,32) and [32,64) are independent
// recurrences; per iteration the block does chain0-step-t then chain1-step-t,
// so each chain's LLC handoff latency hides under the other chain's compute.
// Per chain-step: wave (q, kh) computes gate q's 32x16 tile over its K-half
// (2 m-tiles in-wave, B-frag reused), partials via gst; cell epilogue in
// 512 threads (1 thread = 1 cell); publish h slice (8B agent stores), flag,
// then outputs stores AFTER the flag (off critical path). xproj gate values
// prefetched BEFORE the poll (independent of h). c is register-resident.
// ---------------------------------------------------------------------------
__global__ __launch_bounds__(512) void lstm_chunk(
    const unsigned short* __restrict__ xproj,  // [TC][B][4096] bf16
    const unsigned short* __restrict__ whh,    // [4096][1024] bf16
    const float* __restrict__ bih, const float* __restrict__ bhh,
    unsigned short* __restrict__ hchain,       // [TC+1][B][H] bf16
    float* __restrict__ cbuf,                  // [B][H] f32
    float* __restrict__ outputs,               // [B][T][H] f32
    int* __restrict__ flags,                   // [2*NBLK*FSTR]
    int t0)
{
    __shared__ bf16x8 Ws[64 * 128];            // 128 KB, swizzled 16B slots
    __shared__ float  gst[2][32][66];          // [kh][b][v=q*16+jc] partials
    __shared__ float  hsh[32][17];             // new h slice (one chain)

    const int tid = threadIdx.x;
    const int jb  = blockIdx.x;
    const int j0  = jb * 16;

    // stage W_hh slice: rows v = q*16+jc -> global row q*H + j0 + jc
    #pragma unroll
    for (int it = 0; it < 16; ++it) {
        int f = it * 512 + tid;                // 16B-slot id, 0..8191
        int v = f >> 7, s = f & 127;
        int grow = (v >> 4) * H + j0 + (v & 15);
        Ws[v * 128 + (s ^ (v & 7))] =
            *(const bf16x8*)(whh + (size_t)grow * H + s * 8);
    }

    const int w = tid >> 6, lane = tid & 63;
    const int q = w & 3, kh = w >> 2;          // wave = (gate, K-half)
    const int lr = lane & 15, lg = lane >> 4;
    const int vrow = q * 16 + lr, vx = vrow & 7;

    // epilogue mapping: thread -> (b within chain, jc)
    const int b_e  = tid >> 4;                 // 0..31
    const int jc_e = tid & 15;
    const int hj   = j0 + jc_e;
    float breg[4];
    #pragma unroll
    for (int qq = 0; qq < 4; ++qq)
        breg[qq] = bih[qq * H + hj] + bhh[qq * H + hj];
    float creg[2] = { cbuf[b_e * H + hj], cbuf[(32 + b_e) * H + hj] };
    __syncthreads();

    for (int tcs = 0; tcs < TC; ++tcs) {
        const int target = t0 + tcs;
        // prefetch x_proj gate values for BOTH chains (independent of h)
        float xpv[2][4];
        #pragma unroll
        for (int c = 0; c < 2; ++c)
            #pragma unroll
            for (int qq = 0; qq < 4; ++qq)
                xpv[c][qq] = bf2f(xproj[((size_t)tcs * B + c * 32 + b_e) * G4
                                        + qq * H + hj]);

        const unsigned short* hc     = hchain + (size_t)tcs * B * H;
        unsigned short*       hn_buf = hchain + (size_t)(tcs + 1) * B * H;

        #pragma unroll
        for (int c = 0; c < 2; ++c) {
            if (w == 0) {
                while (true) {
                    int f1 = __hip_atomic_load(&flags[(c * NBLK + lane) * FSTR],
                                __ATOMIC_RELAXED, __HIP_MEMORY_SCOPE_AGENT);
                    if (__all(f1 >= target)) break;
                    __builtin_amdgcn_s_sleep(2);
                }
            }
            __syncthreads();

            const unsigned short* ar0 = hc + (size_t)(c * 32 + lr) * H;
            const unsigned short* ar1 = hc + (size_t)(c * 32 + 16 + lr) * H;
            f32x4 acc0 = {}, acc1 = {};
            #pragma unroll
            for (int ks = 0; ks < 16; ++ks) {
                int k0 = kh * 512 + ks * 32 + lg * 8;
                bf16x8 bw = Ws[vrow * 128 + ((k0 >> 3) ^ vx)];
                bf16x8 a0 = *(const bf16x8*)(ar0 + k0);
                bf16x8 a1 = *(const bf16x8*)(ar1 + k0);
                acc0 = __builtin_amdgcn_mfma_f32_16x16x32_bf16(a0, bw, acc0, 0, 0, 0);
                acc1 = __builtin_amdgcn_mfma_f32_16x16x32_bf16(a1, bw, acc1, 0, 0, 0);
            }
            #pragma unroll
            for (int r = 0; r < 4; ++r) {
                gst[kh][lg * 4 + r][vrow]      = acc0[r];
                gst[kh][16 + lg * 4 + r][vrow] = acc1[r];
            }
            __syncthreads();

            // cell epilogue: 1 thread = 1 (b, j) cell
            float g[4];
            #pragma unroll
            for (int qq = 0; qq < 4; ++qq)
                g[qq] = gst[0][b_e][qq * 16 + jc_e] + gst[1][b_e][qq * 16 + jc_e]
                      + breg[qq] + xpv[c][qq];
            float ig = sigm_f(g[0]);
            float fg = sigm_f(g[1]);
            float gg = tanh_f(g[2]);
            float og = sigm_f(g[3]);
            float cn = fg * creg[c] + ig * gg;
            float hnv = og * tanh_f(cn);
            creg[c] = cn;
            hsh[b_e][jc_e] = hnv;
            __syncthreads();

            // publish h slice: write-through dword stores (2 bf16 each)
            if (tid < 256) {
                int bb = tid >> 3, p = tid & 7;
                unsigned u = (unsigned)f2bf(hsh[bb][2 * p])
                           | ((unsigned)f2bf(hsh[bb][2 * p + 1]) << 16);
                unsigned* dst = (unsigned*)(hn_buf + (size_t)(c * 32 + bb) * H
                                            + j0 + 2 * p);
                __hip_atomic_store(dst, u, __ATOMIC_RELAXED,
                                   __HIP_MEMORY_SCOPE_AGENT);
            }
            __syncthreads();   // all publish stores drained (vmcnt) at exit

            if (tid == 0)
                __hip_atomic_store(&flags[(c * NBLK + jb) * FSTR], target + 1,
                                   __ATOMIC_RELAXED, __HIP_MEMORY_SCOPE_AGENT);

            // outputs store AFTER flag publish — off the handoff critical path
            outputs[((size_t)(c * 32 + b_e) * T + (t0 + tcs)) * H + hj] = hnv;
        }
    }
    cbuf[b_e * H + hj]        = creg[0];
    cbuf[(32 + b_e) * H + hj] = creg[1];
}

// ---------------------------------------------------------------------------
__global__ __launch_bounds__(256) void init_state(
    const float* __restrict__ h0, const float* __restrict__ c0,
    unsigned short* __restrict__ hb, float* __restrict__ cb)
{
    int i = blockIdx.x * 256 + threadIdx.x;
    hb[i] = f2bf(h0[i]);
    cb[i] = c0[i];
}

__global__ __launch_bounds__(128) void reset_flags(int* __restrict__ flags)
{
    __hip_atomic_store(&flags[threadIdx.x * FSTR], 0,
                       __ATOMIC_RELAXED, __HIP_MEMORY_SCOPE_AGENT);
}

__global__ __launch_bounds__(256) void copy_h(
    const unsigned short* __restrict__ src, unsigned short* __restrict__ dst)
{
    int i = blockIdx.x * 256 + threadIdx.x;    // dword index
    ((unsigned*)dst)[i] = ((const unsigned*)src)[i];
}

__global__ __launch_bounds__(256) void finalize(
    const float* __restrict__ outputs, const float* __restrict__ cfin,
    float* __restrict__ outh, float* __restrict__ outc)
{
    int i = blockIdx.x * 256 + threadIdx.x;    // 0..65535
    int b = i >> 10, j = i & 1023;
    outh[i] = outputs[((size_t)b * T + (T - 1)) * H + j];
    outc[i] = cfin[i];
}

// ---------------------------------------------------------------------------
extern "C" void kernel_launch(void* const* d_in, const int* in_sizes, int n_in,
                              void* d_out, int out_size, void* d_ws, size_t ws_size,
                              hipStream_t stream)
{
    const int*   tgt = (const int*)  d_in[0];
    const float* h0  = (const float*)d_in[1];
    const float* c0  = (const float*)d_in[2];
    const float* emb = (const float*)d_in[5];
    const float* Wih = (const float*)d_in[6];
    const float* Whh = (const float*)d_in[7];
    const float* bih = (const float*)d_in[8];
    const float* bhh = (const float*)d_in[9];

    float* out     = (float*)d_out;
    float* outputs = out;                                  // [B][T][H]
    float* out_h   = out + (size_t)B * T * H;
    float* out_c   = out_h + B * H;

    // ws layout — ~56.5 MB
    unsigned short* xproj  = (unsigned short*)d_ws;            // TC*B*G4
    unsigned short* xch    = xproj  + (size_t)TC * B * G4;     // TC*B*H
    unsigned short* wih    = xch    + (size_t)TC * B * H;      // G4*H
    unsigned short* whh    = wih    + (size_t)G4 * H;          // G4*H
    unsigned short* hchain = whh    + (size_t)G4 * H;          // (TC+1)*B*H
    float*          cbuf   = (float*)(hchain + (size_t)(TC + 1) * B * H);
    int*            flags  = (int*)(cbuf + (size_t)B * H);     // 2*NBLK*FSTR

    cast_f32_bf16<<<2048, 256, 0, stream>>>(Wih, wih, (G4 * H) / 8);
    cast_f32_bf16<<<2048, 256, 0, stream>>>(Whh, whh, (G4 * H) / 8);
    init_state<<<(B * H) / 256, 256, 0, stream>>>(h0, c0, hchain, cbuf);
    reset_flags<<<1, 2 * NBLK, 0, stream>>>(flags);

    for (int ci = 0; ci < NCH; ++ci) {
        gather_x<<<(TC * B) / 2, 256, 0, stream>>>(tgt, emb, xch, ci * TC);
        gemm_xproj<<<(TC * B / 128) * (G4 / 128), 256, 0, stream>>>(xch, wih, xproj);
        if (ci) copy_h<<<(B * H / 2) / 256, 256, 0, stream>>>(
                    hchain + (size_t)TC * B * H, hchain);
        int t0 = ci * TC;
        void* args[] = { (void*)&xproj, (void*)&whh, (void*)&bih, (void*)&bhh,
                         (void*)&hchain, (void*)&cbuf, (void*)&outputs,
                         (void*)&flags, (void*)&t0 };
        hipLaunchCooperativeKernel((void*)lstm_chunk, dim3(NBLK), dim3(512),
                                   args, 0, stream);
    }
    finalize<<<(B * H) / 256, 256, 0, stream>>>(outputs, cbuf, out_h, out_c);
}

// Round 7
// 3216.362 us; speedup vs baseline: 1.4134x; 1.4134x over previous
//
#include <hip/hip_runtime.h>
#include <hip/hip_bf16.h>
#include <math.h>

#define B    64
#define T    256
#define H    1024
#define G4   4096
#define TC   64           // timesteps per x_proj chunk
#define NCH  (T / TC)
#define NBLK 128          // persistent blocks (8 h-cols each)
#define FSTR 16           // flag stride in ints (64B apart)

typedef __attribute__((ext_vector_type(8))) short bf16x8;
typedef __attribute__((ext_vector_type(4))) float f32x4;

__device__ __forceinline__ unsigned short f2bf(float x) {
    union { float f; unsigned u; } v; v.f = x;
    unsigned r = v.u + 0x7fffu + ((v.u >> 16) & 1u);   // RNE
    return (unsigned short)(r >> 16);
}
__device__ __forceinline__ float bf2f(unsigned short s) {
    union { unsigned u; float f; } v; v.u = ((unsigned)s) << 16;
    return v.f;
}
__device__ __forceinline__ float sigm_f(float x) {
    return 1.f / (1.f + __expf(-x));
}
__device__ __forceinline__ float tanh_f(float x) {
    float e = __expf(2.f * x);
    return (e - 1.f) / (e + 1.f);
}

// ---------------------------------------------------------------------------
__global__ __launch_bounds__(256) void cast_f32_bf16(
    const float* __restrict__ src, unsigned short* __restrict__ dst, int n8)
{
    int i = blockIdx.x * 256 + threadIdx.x;
    if (i >= n8) return;
    const float4* s = (const float4*)(src + (size_t)i * 8);
    float4 a = s[0], b = s[1];
    bf16x8 o;
    o[0] = f2bf(a.x); o[1] = f2bf(a.y); o[2] = f2bf(a.z); o[3] = f2bf(a.w);
    o[4] = f2bf(b.x); o[5] = f2bf(b.y); o[6] = f2bf(b.z); o[7] = f2bf(b.w);
    *(bf16x8*)(dst + (size_t)i * 8) = o;
}

// ---------------------------------------------------------------------------
__global__ __launch_bounds__(256) void gather_x(
    const int* __restrict__ tgt, const float* __restrict__ emb,
    unsigned short* __restrict__ xch, int t0)
{
    int tid = threadIdx.x;
    int r   = blockIdx.x * 2 + (tid >> 7);     // 0..4095
    int c   = (tid & 127) * 8;
    int b   = r & 63, tcc = r >> 6;
    int token = tgt[b * T + t0 + tcc];
    const float4* s = (const float4*)(emb + (size_t)token * H + c);
    float4 x0 = s[0], x1 = s[1];
    bf16x8 o;
    o[0] = f2bf(x0.x); o[1] = f2bf(x0.y); o[2] = f2bf(x0.z); o[3] = f2bf(x0.w);
    o[4] = f2bf(x1.x); o[5] = f2bf(x1.y); o[6] = f2bf(x1.z); o[7] = f2bf(x1.w);
    *(bf16x8*)(xch + (size_t)r * H + c) = o;
}

// ---------------------------------------------------------------------------
// x_proj chunk GEMM (unchanged — proven since round 2)
// ---------------------------------------------------------------------------
__global__ __launch_bounds__(256) void gemm_xproj(
    const unsigned short* __restrict__ A,   // x chunk bf16 [4096][1024]
    const unsigned short* __restrict__ Bt,  // W_ih bf16 [4096][1024]
    unsigned short* __restrict__ C)         // [4096][4096]
{
    __shared__ unsigned short As[128 * 64], Bs[128 * 64];
    const int tid  = threadIdx.x;
    const int brow = (blockIdx.x >> 5) * 128;
    const int bcol = (blockIdx.x & 31) * 128;
    const int w = tid >> 6, lane = tid & 63;
    const int wr = w >> 1, wc = w & 1;
    const int lr = lane & 15, lg = lane >> 4;

    f32x4 acc[4][4] = {};

    for (int kc = 0; kc < H; kc += 64) {
        if (kc) __syncthreads();
        #pragma unroll
        for (int i = 0; i < 4; ++i) {
            int sf  = i * 256 + tid;
            int row = sf >> 3, s = sf & 7;
            int col = kc + s * 8;
            *(bf16x8*)(As + row * 64 + ((s ^ (row & 7)) * 8)) =
                *(const bf16x8*)(A + (size_t)(brow + row) * H + col);
            *(bf16x8*)(Bs + row * 64 + ((s ^ (row & 7)) * 8)) =
                *(const bf16x8*)(Bt + (size_t)(bcol + row) * H + col);
        }
        __syncthreads();
        #pragma unroll
        for (int kk = 0; kk < 2; ++kk) {
            bf16x8 af[4], bv[4];
            #pragma unroll
            for (int m = 0; m < 4; ++m) {
                int row = wr * 64 + m * 16 + lr;
                int s   = kk * 4 + lg;
                af[m] = *(const bf16x8*)(As + row * 64 + ((s ^ (row & 7)) * 8));
            }
            #pragma unroll
            for (int n = 0; n < 4; ++n) {
                int row = wc * 64 + n * 16 + lr;
                int s   = kk * 4 + lg;
                bv[n] = *(const bf16x8*)(Bs + row * 64 + ((s ^ (row & 7)) * 8));
            }
            #pragma unroll
            for (int m = 0; m < 4; ++m)
                #pragma unroll
                for (int n = 0; n < 4; ++n)
                    acc[m][n] = __builtin_amdgcn_mfma_f32_16x16x32_bf16(
                        af[m], bv[n], acc[m][n], 0, 0, 0);
        }
    }
    #pragma unroll
    for (int m = 0; m < 4; ++m)
        #pragma unroll
        for (int n = 0; n < 4; ++n)
            #pragma unroll
            for (int r = 0; r < 4; ++r) {
                int row = brow + wr * 64 + m * 16 + lg * 4 + r;
                int col = bcol + wc * 64 + n * 16 + lr;
                C[(size_t)row * G4 + col] = f2bf(acc[m][n][r]);
            }
}

// ---------------------------------------------------------------------------
// persistent chunk recurrence, TWO interleaved batch-chains on the round-5
// geometry: 128 blocks x 512 thr, block jb owns h-cols [8jb,8jb+8) x 4 gates
// = 32 W_hh rows in LDS (64 KB, XOR-swizzled; shared by both chains).
// Chains = batch halves [0,32) / [32,64): independent recurrences processed
// alternately so each chain's publish->visibility latency hides under the
// other chain's compute. Per chain-step: wave (m,nt,kh) does 1 m-tile x
// 1 n-tile x 16 k-steps (16 MFMA); partial sums via gst LDS; epilogue
// (tid<256, 1 thread = 1 cell); publish via shfl-packed agent dword stores
// (no LDS round-trip); barrier drains; flag; outputs HBM store after flag.
// All 8 waves poll (no post-poll barrier). xproj prefetched before polls.
// ---------------------------------------------------------------------------
__global__ __launch_bounds__(512) void lstm_chunk(
    const unsigned short* __restrict__ xproj,  // [TC][B][4096] bf16
    const unsigned short* __restrict__ whh,    // [4096][1024] bf16
    const float* __restrict__ bih, const float* __restrict__ bhh,
    unsigned short* __restrict__ hchain,       // [TC+1][B][H] bf16
    float* __restrict__ cbuf,                  // [B][H] f32
    float* __restrict__ outputs,               // [B][T][H] f32
    int* __restrict__ flags,                   // [2*NBLK*FSTR]
    int t0)
{
    __shared__ bf16x8 Ws[32 * 128];            // 64 KB, swizzled 16B slots
    __shared__ float  gst[2][32][33];          // [kh][b in chain][v=q*8+jc]

    const int tid = threadIdx.x;
    const int jb  = blockIdx.x;
    const int j0  = jb * 8;

    // stage W_hh slice: rows v = q*8+jc -> global row q*H + j0 + jc
    #pragma unroll
    for (int it = 0; it < 8; ++it) {
        int f = it * 512 + tid;                // 16B-slot id, 0..4095
        int v = f >> 7, s = f & 127;
        int grow = (v >> 3) * H + j0 + (v & 7);
        Ws[v * 128 + (s ^ (v & 7))] =
            *(const bf16x8*)(whh + (size_t)grow * H + s * 8);
    }

    const int w = tid >> 6, lane = tid & 63;
    const int m = w & 1, nt = (w >> 1) & 1, kh = w >> 2;
    const int lr = lane & 15, lg = lane >> 4;
    const int vrow = nt * 16 + lr, vx = vrow & 7;

    // epilogue mapping (tid < 256): thread -> (b within chain, jc)
    const int b_e  = (tid >> 3) & 31;
    const int jc_e = tid & 7;
    const int hj   = j0 + jc_e;
    float breg[4] = {0.f, 0.f, 0.f, 0.f};
    float creg[2] = {0.f, 0.f};
    if (tid < 256) {
        #pragma unroll
        for (int qq = 0; qq < 4; ++qq)
            breg[qq] = bih[qq * H + hj] + bhh[qq * H + hj];
        creg[0] = cbuf[b_e * H + hj];
        creg[1] = cbuf[(32 + b_e) * H + hj];
    }
    __syncthreads();

    for (int tcs = 0; tcs < TC; ++tcs) {
        const int target = t0 + tcs;

        // prefetch x_proj gate values for BOTH chains (independent of h)
        float xpv[2][4];
        if (tid < 256) {
            #pragma unroll
            for (int c = 0; c < 2; ++c)
                #pragma unroll
                for (int qq = 0; qq < 4; ++qq)
                    xpv[c][qq] = bf2f(xproj[((size_t)tcs * B + c * 32 + b_e) * G4
                                            + qq * H + hj]);
        }

        const unsigned short* hc     = hchain + (size_t)tcs * B * H;
        unsigned short*       hn_buf = hchain + (size_t)(tcs + 1) * B * H;

        #pragma unroll
        for (int c = 0; c < 2; ++c) {
            // ALL waves poll (no barrier needed: h readiness is flag-proven,
            // gst hazards covered by the two barriers below)
            while (true) {
                int f1 = __hip_atomic_load(&flags[(c * NBLK + lane) * FSTR],
                            __ATOMIC_RELAXED, __HIP_MEMORY_SCOPE_AGENT);
                int f2 = __hip_atomic_load(&flags[(c * NBLK + 64 + lane) * FSTR],
                            __ATOMIC_RELAXED, __HIP_MEMORY_SCOPE_AGENT);
                if (__all(f1 >= target && f2 >= target)) break;
                __builtin_amdgcn_s_sleep(2);
            }

            const unsigned short* arow = hc + (size_t)(c * 32 + m * 16 + lr) * H;
            f32x4 acc = {};
            #pragma unroll
            for (int ks = 0; ks < 16; ++ks) {
                int k0 = kh * 512 + ks * 32 + lg * 8;
                bf16x8 bw = Ws[vrow * 128 + ((k0 >> 3) ^ vx)];
                bf16x8 av = *(const bf16x8*)(arow + k0);
                acc = __builtin_amdgcn_mfma_f32_16x16x32_bf16(av, bw, acc, 0, 0, 0);
            }
            #pragma unroll
            for (int r = 0; r < 4; ++r)
                gst[kh][m * 16 + lg * 4 + r][vrow] = acc[r];
            __syncthreads();

            // cell epilogue + direct publish (shfl-packed dword agent stores)
            float hnv = 0.f;
            if (tid < 256) {
                float g[4];
                #pragma unroll
                for (int qq = 0; qq < 4; ++qq)
                    g[qq] = gst[0][b_e][qq * 8 + jc_e]
                          + gst[1][b_e][qq * 8 + jc_e]
                          + breg[qq] + xpv[c][qq];
                float ig = sigm_f(g[0]);
                float fg = sigm_f(g[1]);
                float gg = tanh_f(g[2]);
                float og = sigm_f(g[3]);
                float cn = fg * creg[c] + ig * gg;
                hnv = og * tanh_f(cn);
                creg[c] = cn;
                unsigned my = (unsigned)f2bf(hnv);
                unsigned ot = __shfl_xor(my, 1);
                if ((lane & 1) == 0) {
                    unsigned u = my | (ot << 16);
                    unsigned* dst = (unsigned*)(hn_buf
                        + (size_t)(c * 32 + b_e) * H + hj);   // hj even
                    __hip_atomic_store(dst, u, __ATOMIC_RELAXED,
                                       __HIP_MEMORY_SCOPE_AGENT);
                }
            }
            __syncthreads();   // drains publish stores (vmcnt) in all waves

            if (tid == 0)
                __hip_atomic_store(&flags[(c * NBLK + jb) * FSTR], target + 1,
                                   __ATOMIC_RELAXED, __HIP_MEMORY_SCOPE_AGENT);

            // outputs store AFTER flag publish — off the handoff critical path
            if (tid < 256)
                outputs[((size_t)(c * 32 + b_e) * T + target) * H + hj] = hnv;
        }
    }
    if (tid < 256) {
        cbuf[b_e * H + hj]        = creg[0];
        cbuf[(32 + b_e) * H + hj] = creg[1];
    }
}

// ---------------------------------------------------------------------------
__global__ __launch_bounds__(256) void init_state(
    const float* __restrict__ h0, const float* __restrict__ c0,
    unsigned short* __restrict__ hb, float* __restrict__ cb)
{
    int i = blockIdx.x * 256 + threadIdx.x;
    hb[i] = f2bf(h0[i]);
    cb[i] = c0[i];
}

__global__ __launch_bounds__(256) void reset_flags(int* __restrict__ flags)
{
    __hip_atomic_store(&flags[threadIdx.x * FSTR], 0,
                       __ATOMIC_RELAXED, __HIP_MEMORY_SCOPE_AGENT);
}

__global__ __launch_bounds__(256) void copy_h(
    const unsigned short* __restrict__ src, unsigned short* __restrict__ dst)
{
    int i = blockIdx.x * 256 + threadIdx.x;    // dword index
    ((unsigned*)dst)[i] = ((const unsigned*)src)[i];
}

__global__ __launch_bounds__(256) void finalize(
    const float* __restrict__ outputs, const float* __restrict__ cfin,
    float* __restrict__ outh, float* __restrict__ outc)
{
    int i = blockIdx.x * 256 + threadIdx.x;    // 0..65535
    int b = i >> 10, j = i & 1023;
    outh[i] = outputs[((size_t)b * T + (T - 1)) * H + j];
    outc[i] = cfin[i];
}

// ---------------------------------------------------------------------------
extern "C" void kernel_launch(void* const* d_in, const int* in_sizes, int n_in,
                              void* d_out, int out_size, void* d_ws, size_t ws_size,
                              hipStream_t stream)
{
    const int*   tgt = (const int*)  d_in[0];
    const float* h0  = (const float*)d_in[1];
    const float* c0  = (const float*)d_in[2];
    const float* emb = (const float*)d_in[5];
    const float* Wih = (const float*)d_in[6];
    const float* Whh = (const float*)d_in[7];
    const float* bih = (const float*)d_in[8];
    const float* bhh = (const float*)d_in[9];

    float* out     = (float*)d_out;
    float* outputs = out;                                  // [B][T][H]
    float* out_h   = out + (size_t)B * T * H;
    float* out_c   = out_h + B * H;

    // ws layout — ~56.5 MB
    unsigned short* xproj  = (unsigned short*)d_ws;            // TC*B*G4
    unsigned short* xch    = xproj  + (size_t)TC * B * G4;     // TC*B*H
    unsigned short* wih    = xch    + (size_t)TC * B * H;      // G4*H
    unsigned short* whh    = wih    + (size_t)G4 * H;          // G4*H
    unsigned short* hchain = whh    + (size_t)G4 * H;          // (TC+1)*B*H
    float*          cbuf   = (float*)(hchain + (size_t)(TC + 1) * B * H);
    int*            flags  = (int*)(cbuf + (size_t)B * H);     // 2*NBLK*FSTR

    cast_f32_bf16<<<2048, 256, 0, stream>>>(Wih, wih, (G4 * H) / 8);
    cast_f32_bf16<<<2048, 256, 0, stream>>>(Whh, whh, (G4 * H) / 8);
    init_state<<<(B * H) / 256, 256, 0, stream>>>(h0, c0, hchain, cbuf);
    reset_flags<<<1, 2 * NBLK, 0, stream>>>(flags);

    for (int ci = 0; ci < NCH; ++ci) {
        gather_x<<<(TC * B) / 2, 256, 0, stream>>>(tgt, emb, xch, ci * TC);
        gemm_xproj<<<(TC * B / 128) * (G4 / 128), 256, 0, stream>>>(xch, wih, xproj);
        if (ci) copy_h<<<(B * H / 2) / 256, 256, 0, stream>>>(
                    hchain + (size_t)TC * B * H, hchain);
        int t0 = ci * TC;
        void* args[] = { (void*)&xproj, (void*)&whh, (void*)&bih, (void*)&bhh,
                         (void*)&hchain, (void*)&cbuf, (void*)&outputs,
                         (void*)&flags, (void*)&t0 };
        hipLaunchCooperativeKernel((void*)lstm_chunk, dim3(NBLK), dim3(512),
                                   args, 0, stream);
    }
    finalize<<<(B * H) / 256, 256, 0, stream>>>(outputs, cbuf, out_h, out_c);
}

// Round 8
// 2911.506 us; speedup vs baseline: 1.5614x; 1.1047x over previous
//
#include <hip/hip_runtime.h>
#include <hip/hip_bf16.h>
#include <math.h>

#define B    64
#define T    256
#define H    1024
#define G4   4096
#define TC   64           // timesteps per x_proj chunk
#define NCH  (T / TC)
#define NBLK 128          // persistent blocks (8 h-cols each)
#define FSTR 16           // flag stride in ints (64B apart)

typedef __attribute__((ext_vector_type(8))) short bf16x8;
typedef __attribute__((ext_vector_type(4))) float f32x4;

__device__ __forceinline__ unsigned short f2bf(float x) {
    union { float f; unsigned u; } v; v.f = x;
    unsigned r = v.u + 0x7fffu + ((v.u >> 16) & 1u);   // RNE
    return (unsigned short)(r >> 16);
}
__device__ __forceinline__ float bf2f(unsigned short s) {
    union { unsigned u; float f; } v; v.u = ((unsigned)s) << 16;
    return v.f;
}
__device__ __forceinline__ float sigm_f(float x) {
    return 1.f / (1.f + __expf(-x));
}
__device__ __forceinline__ float tanh_f(float x) {
    float e = __expf(2.f * x);
    return (e - 1.f) / (e + 1.f);
}

// ---------------------------------------------------------------------------
__global__ __launch_bounds__(256) void cast_f32_bf16(
    const float* __restrict__ src, unsigned short* __restrict__ dst, int n8)
{
    int i = blockIdx.x * 256 + threadIdx.x;
    if (i >= n8) return;
    const float4* s = (const float4*)(src + (size_t)i * 8);
    float4 a = s[0], b = s[1];
    bf16x8 o;
    o[0] = f2bf(a.x); o[1] = f2bf(a.y); o[2] = f2bf(a.z); o[3] = f2bf(a.w);
    o[4] = f2bf(b.x); o[5] = f2bf(b.y); o[6] = f2bf(b.z); o[7] = f2bf(b.w);
    *(bf16x8*)(dst + (size_t)i * 8) = o;
}

// ---------------------------------------------------------------------------
__global__ __launch_bounds__(256) void gather_x(
    const int* __restrict__ tgt, const float* __restrict__ emb,
    unsigned short* __restrict__ xch, int t0)
{
    int tid = threadIdx.x;
    int r   = blockIdx.x * 2 + (tid >> 7);     // 0..4095
    int c   = (tid & 127) * 8;
    int b   = r & 63, tcc = r >> 6;
    int token = tgt[b * T + t0 + tcc];
    const float4* s = (const float4*)(emb + (size_t)token * H + c);
    float4 x0 = s[0], x1 = s[1];
    bf16x8 o;
    o[0] = f2bf(x0.x); o[1] = f2bf(x0.y); o[2] = f2bf(x0.z); o[3] = f2bf(x0.w);
    o[4] = f2bf(x1.x); o[5] = f2bf(x1.y); o[6] = f2bf(x1.z); o[7] = f2bf(x1.w);
    *(bf16x8*)(xch + (size_t)r * H + c) = o;
}

// ---------------------------------------------------------------------------
// x_proj chunk GEMM (unchanged — proven since round 2)
// ---------------------------------------------------------------------------
__global__ __launch_bounds__(256) void gemm_xproj(
    const unsigned short* __restrict__ A,   // x chunk bf16 [4096][1024]
    const unsigned short* __restrict__ Bt,  // W_ih bf16 [4096][1024]
    unsigned short* __restrict__ C)         // [4096][4096]
{
    __shared__ unsigned short As[128 * 64], Bs[128 * 64];
    const int tid  = threadIdx.x;
    const int brow = (blockIdx.x >> 5) * 128;
    const int bcol = (blockIdx.x & 31) * 128;
    const int w = tid >> 6, lane = tid & 63;
    const int wr = w >> 1, wc = w & 1;
    const int lr = lane & 15, lg = lane >> 4;

    f32x4 acc[4][4] = {};

    for (int kc = 0; kc < H; kc += 64) {
        if (kc) __syncthreads();
        #pragma unroll
        for (int i = 0; i < 4; ++i) {
            int sf  = i * 256 + tid;
            int row = sf >> 3, s = sf & 7;
            int col = kc + s * 8;
            *(bf16x8*)(As + row * 64 + ((s ^ (row & 7)) * 8)) =
                *(const bf16x8*)(A + (size_t)(brow + row) * H + col);
            *(bf16x8*)(Bs + row * 64 + ((s ^ (row & 7)) * 8)) =
                *(const bf16x8*)(Bt + (size_t)(bcol + row) * H + col);
        }
        __syncthreads();
        #pragma unroll
        for (int kk = 0; kk < 2; ++kk) {
            bf16x8 af[4], bv[4];
            #pragma unroll
            for (int m = 0; m < 4; ++m) {
                int row = wr * 64 + m * 16 + lr;
                int s   = kk * 4 + lg;
                af[m] = *(const bf16x8*)(As + row * 64 + ((s ^ (row & 7)) * 8));
            }
            #pragma unroll
            for (int n = 0; n < 4; ++n) {
                int row = wc * 64 + n * 16 + lr;
                int s   = kk * 4 + lg;
                bv[n] = *(const bf16x8*)(Bs + row * 64 + ((s ^ (row & 7)) * 8));
            }
            #pragma unroll
            for (int m = 0; m < 4; ++m)
                #pragma unroll
                for (int n = 0; n < 4; ++n)
                    acc[m][n] = __builtin_amdgcn_mfma_f32_16x16x32_bf16(
                        af[m], bv[n], acc[m][n], 0, 0, 0);
        }
    }
    #pragma unroll
    for (int m = 0; m < 4; ++m)
        #pragma unroll
        for (int n = 0; n < 4; ++n)
            #pragma unroll
            for (int r = 0; r < 4; ++r) {
                int row = brow + wr * 64 + m * 16 + lg * 4 + r;
                int col = bcol + wc * 64 + n * 16 + lr;
                C[(size_t)row * G4 + col] = f2bf(acc[m][n][r]);
            }
}

// ---------------------------------------------------------------------------
// persistent chunk recurrence, TWO interleaved batch-chains (r7 skeleton)
// with three fixes:
//  (a) outputs register-buffered 8 steps (phase-unrolled for static index),
//      flushed after flag publish -> HBM-store vmcnt drain paid 1x per 8
//      steps instead of every chain-step;
//  (b) distributed flag poll: wave w owns flags [16w,16w+16), one barrier
//      after -> 8x less LLC flag-line traffic than all-wave full polling;
//  (c) gst padded [34] -> epilogue reads 4-way max (was 8-way with [33]).
// ---------------------------------------------------------------------------
__global__ __launch_bounds__(512) void lstm_chunk(
    const unsigned short* __restrict__ xproj,  // [TC][B][4096] bf16
    const unsigned short* __restrict__ whh,    // [4096][1024] bf16
    const float* __restrict__ bih, const float* __restrict__ bhh,
    unsigned short* __restrict__ hchain,       // [TC+1][B][H] bf16
    float* __restrict__ cbuf,                  // [B][H] f32
    float* __restrict__ outputs,               // [B][T][H] f32
    int* __restrict__ flags,                   // [2*NBLK*FSTR]
    int t0)
{
    __shared__ bf16x8 Ws[32 * 128];            // 64 KB, swizzled 16B slots
    __shared__ float  gst[2][32][34];          // [kh][b in chain][v=q*8+jc]

    const int tid = threadIdx.x;
    const int jb  = blockIdx.x;
    const int j0  = jb * 8;

    // stage W_hh slice: rows v = q*8+jc -> global row q*H + j0 + jc
    #pragma unroll
    for (int it = 0; it < 8; ++it) {
        int f = it * 512 + tid;                // 16B-slot id, 0..4095
        int v = f >> 7, s = f & 127;
        int grow = (v >> 3) * H + j0 + (v & 7);
        Ws[v * 128 + (s ^ (v & 7))] =
            *(const bf16x8*)(whh + (size_t)grow * H + s * 8);
    }

    const int w = tid >> 6, lane = tid & 63;
    const int m = w & 1, nt = (w >> 1) & 1, kh = w >> 2;
    const int lr = lane & 15, lg = lane >> 4;
    const int vrow = nt * 16 + lr, vx = vrow & 7;
    const int fl_base = (w << 4) | (lane & 15);  // this wave's 16 flags

    // epilogue mapping (tid < 256): thread -> (b within chain, jc)
    const int b_e  = (tid >> 3) & 31;
    const int jc_e = tid & 7;
    const int hj   = j0 + jc_e;
    float breg[4] = {0.f, 0.f, 0.f, 0.f};
    float creg[2] = {0.f, 0.f};
    if (tid < 256) {
        #pragma unroll
        for (int qq = 0; qq < 4; ++qq)
            breg[qq] = bih[qq * H + hj] + bhh[qq * H + hj];
        creg[0] = cbuf[b_e * H + hj];
        creg[1] = cbuf[(32 + b_e) * H + hj];
    }
    __syncthreads();

// one chain-step; c is a literal, OSLOT a named float lvalue (static index)
#define CHAIN_STEP(c, OSLOT)                                                  \
    {                                                                         \
        /* distributed poll: wave w checks its 16 flags, then barrier */      \
        while (true) {                                                        \
            int f1 = __hip_atomic_load(&flags[((c) * NBLK + fl_base) * FSTR], \
                        __ATOMIC_RELAXED, __HIP_MEMORY_SCOPE_AGENT);          \
            if (__all(f1 >= target)) break;                                   \
            __builtin_amdgcn_s_sleep(4);                                      \
        }                                                                     \
        __syncthreads();                                                      \
        const unsigned short* arow =                                          \
            hc + (size_t)((c) * 32 + m * 16 + lr) * H;                        \
        f32x4 acc = {};                                                       \
        _Pragma("unroll")                                                     \
        for (int ks = 0; ks < 16; ++ks) {                                     \
            int k0 = kh * 512 + ks * 32 + lg * 8;                             \
            bf16x8 bw = Ws[vrow * 128 + ((k0 >> 3) ^ vx)];                    \
            bf16x8 av = *(const bf16x8*)(arow + k0);                          \
            acc = __builtin_amdgcn_mfma_f32_16x16x32_bf16(av, bw, acc,        \
                                                          0, 0, 0);           \
        }                                                                     \
        _Pragma("unroll")                                                     \
        for (int r = 0; r < 4; ++r)                                           \
            gst[kh][m * 16 + lg * 4 + r][vrow] = acc[r];                      \
        __syncthreads();                                                      \
        if (tid < 256) {                                                      \
            float g[4];                                                       \
            _Pragma("unroll")                                                 \
            for (int qq = 0; qq < 4; ++qq)                                    \
                g[qq] = gst[0][b_e][qq * 8 + jc_e]                            \
                      + gst[1][b_e][qq * 8 + jc_e]                            \
                      + breg[qq] + xpv[c][qq];                                \
            float ig = sigm_f(g[0]);                                          \
            float fg = sigm_f(g[1]);                                          \
            float gg = tanh_f(g[2]);                                          \
            float og = sigm_f(g[3]);                                          \
            float cn = fg * creg[c] + ig * gg;                                \
            float hnv = og * tanh_f(cn);                                      \
            creg[c] = cn;                                                     \
            OSLOT = hnv;                                                      \
            unsigned my = (unsigned)f2bf(hnv);                                \
            unsigned ot = __shfl_xor(my, 1);                                  \
            if ((lane & 1) == 0) {                                            \
                unsigned u = my | (ot << 16);                                 \
                unsigned* dst = (unsigned*)(hn_buf                            \
                    + (size_t)((c) * 32 + b_e) * H + hj);                     \
                __hip_atomic_store(dst, u, __ATOMIC_RELAXED,                  \
                                   __HIP_MEMORY_SCOPE_AGENT);                 \
            }                                                                 \
        }                                                                     \
        __syncthreads();   /* drains publish stores (vmcnt) in all waves */   \
        if (tid == 0)                                                         \
            __hip_atomic_store(&flags[((c) * NBLK + jb) * FSTR], target + 1,  \
                               __ATOMIC_RELAXED, __HIP_MEMORY_SCOPE_AGENT);   \
    }

    for (int tc8 = 0; tc8 < TC; tc8 += 8) {
        float oreg0[8], oreg1[8];
        #pragma unroll
        for (int p = 0; p < 8; ++p) {
            const int tcs    = tc8 + p;
            const int target = t0 + tcs;

            // prefetch x_proj gate values for BOTH chains (independent of h)
            float xpv[2][4];
            if (tid < 256) {
                #pragma unroll
                for (int c = 0; c < 2; ++c)
                    #pragma unroll
                    for (int qq = 0; qq < 4; ++qq)
                        xpv[c][qq] = bf2f(
                            xproj[((size_t)tcs * B + c * 32 + b_e) * G4
                                  + qq * H + hj]);
            }

            const unsigned short* hc     = hchain + (size_t)tcs * B * H;
            unsigned short*       hn_buf = hchain + (size_t)(tcs + 1) * B * H;

            CHAIN_STEP(0, oreg0[p])
            CHAIN_STEP(1, oreg1[p])
        }
        // flush outputs (HBM) once per 8 steps — off the handoff path
        if (tid < 256) {
            #pragma unroll
            for (int p = 0; p < 8; ++p) {
                int t = t0 + tc8 + p;
                outputs[((size_t)b_e * T + t) * H + hj]        = oreg0[p];
                outputs[((size_t)(32 + b_e) * T + t) * H + hj] = oreg1[p];
            }
        }
    }
#undef CHAIN_STEP

    if (tid < 256) {
        cbuf[b_e * H + hj]        = creg[0];
        cbuf[(32 + b_e) * H + hj] = creg[1];
    }
}

// ---------------------------------------------------------------------------
__global__ __launch_bounds__(256) void init_state(
    const float* __restrict__ h0, const float* __restrict__ c0,
    unsigned short* __restrict__ hb, float* __restrict__ cb)
{
    int i = blockIdx.x * 256 + threadIdx.x;
    hb[i] = f2bf(h0[i]);
    cb[i] = c0[i];
}

__global__ __launch_bounds__(256) void reset_flags(int* __restrict__ flags)
{
    __hip_atomic_store(&flags[threadIdx.x * FSTR], 0,
                       __ATOMIC_RELAXED, __HIP_MEMORY_SCOPE_AGENT);
}

__global__ __launch_bounds__(256) void copy_h(
    const unsigned short* __restrict__ src, unsigned short* __restrict__ dst)
{
    int i = blockIdx.x * 256 + threadIdx.x;    // dword index
    ((unsigned*)dst)[i] = ((const unsigned*)src)[i];
}

__global__ __launch_bounds__(256) void finalize(
    const float* __restrict__ outputs, const float* __restrict__ cfin,
    float* __restrict__ outh, float* __restrict__ outc)
{
    int i = blockIdx.x * 256 + threadIdx.x;    // 0..65535
    int b = i >> 10, j = i & 1023;
    outh[i] = outputs[((size_t)b * T + (T - 1)) * H + j];
    outc[i] = cfin[i];
}

// ---------------------------------------------------------------------------
extern "C" void kernel_launch(void* const* d_in, const int* in_sizes, int n_in,
                              void* d_out, int out_size, void* d_ws, size_t ws_size,
                              hipStream_t stream)
{
    const int*   tgt = (const int*)  d_in[0];
    const float* h0  = (const float*)d_in[1];
    const float* c0  = (const float*)d_in[2];
    const float* emb = (const float*)d_in[5];
    const float* Wih = (const float*)d_in[6];
    const float* Whh = (const float*)d_in[7];
    const float* bih = (const float*)d_in[8];
    const float* bhh = (const float*)d_in[9];

    float* out     = (float*)d_out;
    float* outputs = out;                                  // [B][T][H]
    float* out_h   = out + (size_t)B * T * H;
    float* out_c   = out_h + B * H;

    // ws layout — ~56.5 MB
    unsigned short* xproj  = (unsigned short*)d_ws;            // TC*B*G4
    unsigned short* xch    = xproj  + (size_t)TC * B * G4;     // TC*B*H
    unsigned short* wih    = xch    + (size_t)TC * B * H;      // G4*H
    unsigned short* whh    = wih    + (size_t)G4 * H;          // G4*H
    unsigned short* hchain = whh    + (size_t)G4 * H;          // (TC+1)*B*H
    float*          cbuf   = (float*)(hchain + (size_t)(TC + 1) * B * H);
    int*            flags  = (int*)(cbuf + (size_t)B * H);     // 2*NBLK*FSTR

    cast_f32_bf16<<<2048, 256, 0, stream>>>(Wih, wih, (G4 * H) / 8);
    cast_f32_bf16<<<2048, 256, 0, stream>>>(Whh, whh, (G4 * H) / 8);
    init_state<<<(B * H) / 256, 256, 0, stream>>>(h0, c0, hchain, cbuf);
    reset_flags<<<1, 2 * NBLK, 0, stream>>>(flags);

    for (int ci = 0; ci < NCH; ++ci) {
        gather_x<<<(TC * B) / 2, 256, 0, stream>>>(tgt, emb, xch, ci * TC);
        gemm_xproj<<<(TC * B / 128) * (G4 / 128), 256, 0, stream>>>(xch, wih, xproj);
        if (ci) copy_h<<<(B * H / 2) / 256, 256, 0, stream>>>(
                    hchain + (size_t)TC * B * H, hchain);
        int t0 = ci * TC;
        void* args[] = { (void*)&xproj, (void*)&whh, (void*)&bih, (void*)&bhh,
                         (void*)&hchain, (void*)&cbuf, (void*)&outputs,
                         (void*)&flags, (void*)&t0 };
        hipLaunchCooperativeKernel((void*)lstm_chunk, dim3(NBLK), dim3(512),
                                   args, 0, stream);
    }
    finalize<<<(B * H) / 256, 256, 0, stream>>>(outputs, cbuf, out_h, out_c);
}

// Round 9
// 2617.651 us; speedup vs baseline: 1.7367x; 1.1123x over previous
//
#include <hip/hip_runtime.h>
#include <hip/hip_bf16.h>
#include <math.h>

#define B    64
#define T    256
#define H    1024
#define G4   4096
#define TC   64           // timesteps per x_proj chunk
#define NCH  (T / TC)
#define NBLK 128          // persistent blocks (8 h-cols each)
#define FSTR 16           // flag stride in ints (64B apart)

typedef __attribute__((ext_vector_type(8))) short bf16x8;
typedef __attribute__((ext_vector_type(4))) float f32x4;

__device__ __forceinline__ unsigned short f2bf(float x) {
    union { float f; unsigned u; } v; v.f = x;
    unsigned r = v.u + 0x7fffu + ((v.u >> 16) & 1u);   // RNE
    return (unsigned short)(r >> 16);
}
__device__ __forceinline__ float bf2f(unsigned short s) {
    union { unsigned u; float f; } v; v.u = ((unsigned)s) << 16;
    return v.f;
}
__device__ __forceinline__ float sigm_f(float x) {
    return 1.f / (1.f + __expf(-x));
}
__device__ __forceinline__ float tanh_f(float x) {
    float e = __expf(2.f * x);
    return (e - 1.f) / (e + 1.f);
}

// ---------------------------------------------------------------------------
__global__ __launch_bounds__(256) void cast_f32_bf16(
    const float* __restrict__ src, unsigned short* __restrict__ dst, int n8)
{
    int i = blockIdx.x * 256 + threadIdx.x;
    if (i >= n8) return;
    const float4* s = (const float4*)(src + (size_t)i * 8);
    float4 a = s[0], b = s[1];
    bf16x8 o;
    o[0] = f2bf(a.x); o[1] = f2bf(a.y); o[2] = f2bf(a.z); o[3] = f2bf(a.w);
    o[4] = f2bf(b.x); o[5] = f2bf(b.y); o[6] = f2bf(b.z); o[7] = f2bf(b.w);
    *(bf16x8*)(dst + (size_t)i * 8) = o;
}

// ---------------------------------------------------------------------------
__global__ __launch_bounds__(256) void gather_x(
    const int* __restrict__ tgt, const float* __restrict__ emb,
    unsigned short* __restrict__ xch, int t0)
{
    int tid = threadIdx.x;
    int r   = blockIdx.x * 2 + (tid >> 7);     // 0..4095
    int c   = (tid & 127) * 8;
    int b   = r & 63, tcc = r >> 6;
    int token = tgt[b * T + t0 + tcc];
    const float4* s = (const float4*)(emb + (size_t)token * H + c);
    float4 x0 = s[0], x1 = s[1];
    bf16x8 o;
    o[0] = f2bf(x0.x); o[1] = f2bf(x0.y); o[2] = f2bf(x0.z); o[3] = f2bf(x0.w);
    o[4] = f2bf(x1.x); o[5] = f2bf(x1.y); o[6] = f2bf(x1.z); o[7] = f2bf(x1.w);
    *(bf16x8*)(xch + (size_t)r * H + c) = o;
}

// ---------------------------------------------------------------------------
// x_proj chunk GEMM (unchanged — proven since round 2)
// ---------------------------------------------------------------------------
__global__ __launch_bounds__(256) void gemm_xproj(
    const unsigned short* __restrict__ A,   // x chunk bf16 [4096][1024]
    const unsigned short* __restrict__ Bt,  // W_ih bf16 [4096][1024]
    unsigned short* __restrict__ C)         // [4096][4096]
{
    __shared__ unsigned short As[128 * 64], Bs[128 * 64];
    const int tid  = threadIdx.x;
    const int brow = (blockIdx.x >> 5) * 128;
    const int bcol = (blockIdx.x & 31) * 128;
    const int w = tid >> 6, lane = tid & 63;
    const int wr = w >> 1, wc = w & 1;
    const int lr = lane & 15, lg = lane >> 4;

    f32x4 acc[4][4] = {};

    for (int kc = 0; kc < H; kc += 64) {
        if (kc) __syncthreads();
        #pragma unroll
        for (int i = 0; i < 4; ++i) {
            int sf  = i * 256 + tid;
            int row = sf >> 3, s = sf & 7;
            int col = kc + s * 8;
            *(bf16x8*)(As + row * 64 + ((s ^ (row & 7)) * 8)) =
                *(const bf16x8*)(A + (size_t)(brow + row) * H + col);
            *(bf16x8*)(Bs + row * 64 + ((s ^ (row & 7)) * 8)) =
                *(const bf16x8*)(Bt + (size_t)(bcol + row) * H + col);
        }
        __syncthreads();
        #pragma unroll
        for (int kk = 0; kk < 2; ++kk) {
            bf16x8 af[4], bv[4];
            #pragma unroll
            for (int m = 0; m < 4; ++m) {
                int row = wr * 64 + m * 16 + lr;
                int s   = kk * 4 + lg;
                af[m] = *(const bf16x8*)(As + row * 64 + ((s ^ (row & 7)) * 8));
            }
            #pragma unroll
            for (int n = 0; n < 4; ++n) {
                int row = wc * 64 + n * 16 + lr;
                int s   = kk * 4 + lg;
                bv[n] = *(const bf16x8*)(Bs + row * 64 + ((s ^ (row & 7)) * 8));
            }
            #pragma unroll
            for (int m = 0; m < 4; ++m)
                #pragma unroll
                for (int n = 0; n < 4; ++n)
                    acc[m][n] = __builtin_amdgcn_mfma_f32_16x16x32_bf16(
                        af[m], bv[n], acc[m][n], 0, 0, 0);
        }
    }
    #pragma unroll
    for (int m = 0; m < 4; ++m)
        #pragma unroll
        for (int n = 0; n < 4; ++n)
            #pragma unroll
            for (int r = 0; r < 4; ++r) {
                int row = brow + wr * 64 + m * 16 + lg * 4 + r;
                int col = bcol + wc * 64 + n * 16 + lr;
                C[(size_t)row * G4 + col] = f2bf(acc[m][n][r]);
            }
}

// ---------------------------------------------------------------------------
// persistent chunk recurrence — SINGLE chain (all 64 batches per step), the
// r5 wave layout plus every r8 micro-fix, so the per-step serial LLC path
// (poll -> h load -> MFMA -> epilogue -> publish-drain -> flag) is paid ONCE
// per t instead of twice:
//  * wave (m 0..3, nt 0..1): 16x16 tile over FULL K=1024 (32 MFMA), no
//    K-split reduction;
//  * xpv prefetched before the poll; outputs reg-buffered 8 steps and
//    flushed after flag publish; distributed poll (wave w owns 16 flags);
//    shfl-packed publish direct from registers; all 512 threads in the
//    epilogue (1 thread = 1 cell); gst stride 36 (reads <=2-way).
// ---------------------------------------------------------------------------
__global__ __launch_bounds__(512) void lstm_chunk(
    const unsigned short* __restrict__ xproj,  // [TC][B][4096] bf16
    const unsigned short* __restrict__ whh,    // [4096][1024] bf16
    const float* __restrict__ bih, const float* __restrict__ bhh,
    unsigned short* __restrict__ hchain,       // [TC+1][B][H] bf16
    float* __restrict__ cbuf,                  // [B][H] f32
    float* __restrict__ outputs,               // [B][T][H] f32
    int* __restrict__ flags,                   // [NBLK*FSTR]
    int t0)
{
    __shared__ bf16x8 Ws[32 * 128];            // 64 KB, swizzled 16B slots
    __shared__ float  gst[64][36];             // [batch][v=q*8+jc], stride 36

    const int tid = threadIdx.x;
    const int jb  = blockIdx.x;
    const int j0  = jb * 8;

    // stage W_hh slice: rows v = q*8+jc -> global row q*H + j0 + jc
    #pragma unroll
    for (int it = 0; it < 8; ++it) {
        int f = it * 512 + tid;                // 16B-slot id, 0..4095
        int v = f >> 7, s = f & 127;
        int grow = (v >> 3) * H + j0 + (v & 7);
        Ws[v * 128 + (s ^ (v & 7))] =
            *(const bf16x8*)(whh + (size_t)grow * H + s * 8);
    }

    const int w = tid >> 6, lane = tid & 63;
    const int m = w & 3, nt = w >> 2;          // wave = (m-tile, n-tile)
    const int lr = lane & 15, lg = lane >> 4;
    const int vrow = nt * 16 + lr, vx = vrow & 7;
    const int fl_base = (w << 4) | (lane & 15);  // this wave's 16 flags

    // epilogue mapping: all 512 threads, 1 thread = 1 (b, jc) cell
    const int b_e  = tid >> 3;                 // 0..63
    const int jc_e = tid & 7;
    const int hj   = j0 + jc_e;
    float breg[4];
    #pragma unroll
    for (int qq = 0; qq < 4; ++qq)
        breg[qq] = bih[qq * H + hj] + bhh[qq * H + hj];
    float creg = cbuf[b_e * H + hj];
    __syncthreads();

    for (int tc8 = 0; tc8 < TC; tc8 += 8) {
        float oreg[8];
        #pragma unroll
        for (int p = 0; p < 8; ++p) {
            const int tcs    = tc8 + p;
            const int target = t0 + tcs;

            // prefetch x_proj gate values (independent of h)
            float xpv[4];
            #pragma unroll
            for (int qq = 0; qq < 4; ++qq)
                xpv[qq] = bf2f(xproj[((size_t)tcs * B + b_e) * G4
                                     + qq * H + hj]);

            const unsigned short* hc     = hchain + (size_t)tcs * B * H;
            unsigned short*       hn_buf = hchain + (size_t)(tcs + 1) * B * H;

            // distributed poll: wave w checks its 16 flags, barrier joins
            while (true) {
                int f1 = __hip_atomic_load(&flags[fl_base * FSTR],
                            __ATOMIC_RELAXED, __HIP_MEMORY_SCOPE_AGENT);
                if (__all(f1 >= target)) break;
                __builtin_amdgcn_s_sleep(2);
            }
            __syncthreads();

            // h @ W_hh^T : full K per wave, 32 MFMA
            const unsigned short* arow = hc + (size_t)(m * 16 + lr) * H;
            f32x4 acc = {};
            #pragma unroll
            for (int ks = 0; ks < 32; ++ks) {
                int k0 = ks * 32 + lg * 8;
                bf16x8 bw = Ws[vrow * 128 + ((ks * 4 + lg) ^ vx)];
                bf16x8 av = *(const bf16x8*)(arow + k0);
                acc = __builtin_amdgcn_mfma_f32_16x16x32_bf16(av, bw, acc,
                                                              0, 0, 0);
            }
            #pragma unroll
            for (int r = 0; r < 4; ++r)
                gst[m * 16 + lg * 4 + r][vrow] = acc[r];
            __syncthreads();

            // cell epilogue + direct publish (shfl-packed dword agent stores)
            {
                float g[4];
                #pragma unroll
                for (int qq = 0; qq < 4; ++qq)
                    g[qq] = gst[b_e][qq * 8 + jc_e] + breg[qq] + xpv[qq];
                float ig = sigm_f(g[0]);
                float fg = sigm_f(g[1]);
                float gg = tanh_f(g[2]);
                float og = sigm_f(g[3]);
                float cn = fg * creg + ig * gg;
                float hnv = og * tanh_f(cn);
                creg = cn;
                oreg[p] = hnv;
                unsigned my = (unsigned)f2bf(hnv);
                unsigned ot = __shfl_xor(my, 1);
                if ((lane & 1) == 0) {
                    unsigned u = my | (ot << 16);
                    unsigned* dst = (unsigned*)(hn_buf
                        + (size_t)b_e * H + hj);          // hj even
                    __hip_atomic_store(dst, u, __ATOMIC_RELAXED,
                                       __HIP_MEMORY_SCOPE_AGENT);
                }
            }
            __syncthreads();   // drains publish stores (vmcnt) in all waves

            if (tid == 0)
                __hip_atomic_store(&flags[jb * FSTR], target + 1,
                                   __ATOMIC_RELAXED, __HIP_MEMORY_SCOPE_AGENT);
        }
        // flush outputs (HBM) once per 8 steps — off the handoff path
        #pragma unroll
        for (int p = 0; p < 8; ++p) {
            int t = t0 + tc8 + p;
            outputs[((size_t)b_e * T + t) * H + hj] = oreg[p];
        }
    }

    cbuf[b_e * H + hj] = creg;
}

// ---------------------------------------------------------------------------
__global__ __launch_bounds__(256) void init_state(
    const float* __restrict__ h0, const float* __restrict__ c0,
    unsigned short* __restrict__ hb, float* __restrict__ cb)
{
    int i = blockIdx.x * 256 + threadIdx.x;
    hb[i] = f2bf(h0[i]);
    cb[i] = c0[i];
}

__global__ __launch_bounds__(128) void reset_flags(int* __restrict__ flags)
{
    __hip_atomic_store(&flags[threadIdx.x * FSTR], 0,
                       __ATOMIC_RELAXED, __HIP_MEMORY_SCOPE_AGENT);
}

__global__ __launch_bounds__(256) void copy_h(
    const unsigned short* __restrict__ src, unsigned short* __restrict__ dst)
{
    int i = blockIdx.x * 256 + threadIdx.x;    // dword index
    ((unsigned*)dst)[i] = ((const unsigned*)src)[i];
}

__global__ __launch_bounds__(256) void finalize(
    const float* __restrict__ outputs, const float* __restrict__ cfin,
    float* __restrict__ outh, float* __restrict__ outc)
{
    int i = blockIdx.x * 256 + threadIdx.x;    // 0..65535
    int b = i >> 10, j = i & 1023;
    outh[i] = outputs[((size_t)b * T + (T - 1)) * H + j];
    outc[i] = cfin[i];
}

// ---------------------------------------------------------------------------
extern "C" void kernel_launch(void* const* d_in, const int* in_sizes, int n_in,
                              void* d_out, int out_size, void* d_ws, size_t ws_size,
                              hipStream_t stream)
{
    const int*   tgt = (const int*)  d_in[0];
    const float* h0  = (const float*)d_in[1];
    const float* c0  = (const float*)d_in[2];
    const float* emb = (const float*)d_in[5];
    const float* Wih = (const float*)d_in[6];
    const float* Whh = (const float*)d_in[7];
    const float* bih = (const float*)d_in[8];
    const float* bhh = (const float*)d_in[9];

    float* out     = (float*)d_out;
    float* outputs = out;                                  // [B][T][H]
    float* out_h   = out + (size_t)B * T * H;
    float* out_c   = out_h + B * H;

    // ws layout — ~56.5 MB
    unsigned short* xproj  = (unsigned short*)d_ws;            // TC*B*G4
    unsigned short* xch    = xproj  + (size_t)TC * B * G4;     // TC*B*H
    unsigned short* wih    = xch    + (size_t)TC * B * H;      // G4*H
    unsigned short* whh    = wih    + (size_t)G4 * H;          // G4*H
    unsigned short* hchain = whh    + (size_t)G4 * H;          // (TC+1)*B*H
    float*          cbuf   = (float*)(hchain + (size_t)(TC + 1) * B * H);
    int*            flags  = (int*)(cbuf + (size_t)B * H);     // NBLK*FSTR

    cast_f32_bf16<<<2048, 256, 0, stream>>>(Wih, wih, (G4 * H) / 8);
    cast_f32_bf16<<<2048, 256, 0, stream>>>(Whh, whh, (G4 * H) / 8);
    init_state<<<(B * H) / 256, 256, 0, stream>>>(h0, c0, hchain, cbuf);
    reset_flags<<<1, NBLK, 0, stream>>>(flags);

    for (int ci = 0; ci < NCH; ++ci) {
        gather_x<<<(TC * B) / 2, 256, 0, stream>>>(tgt, emb, xch, ci * TC);
        gemm_xproj<<<(TC * B / 128) * (G4 / 128), 256, 0, stream>>>(xch, wih, xproj);
        if (ci) copy_h<<<(B * H / 2) / 256, 256, 0, stream>>>(
                    hchain + (size_t)TC * B * H, hchain);
        int t0 = ci * TC;
        void* args[] = { (void*)&xproj, (void*)&whh, (void*)&bih, (void*)&bhh,
                         (void*)&hchain, (void*)&cbuf, (void*)&outputs,
                         (void*)&flags, (void*)&t0 };
        hipLaunchCooperativeKernel((void*)lstm_chunk, dim3(NBLK), dim3(512),
                                   args, 0, stream);
    }
    finalize<<<(B * H) / 256, 256, 0, stream>>>(outputs, cbuf, out_h, out_c);
}